// Round 9
// baseline (706.560 us; speedup 1.0000x reference)
//
#include <hip/hip_runtime.h>
#include <hip/hip_bf16.h>

#define NUM_STEPS 10
#define DT 0.1f

typedef __bf16 bf16_t;
typedef __bf16 bf16x8 __attribute__((ext_vector_type(8)));
typedef float f32x4 __attribute__((ext_vector_type(4)));

// one-shot: decay[h] = exp(-dt/tau[h])
__global__ void make_decay(const float* __restrict__ tau,
                           float* __restrict__ decay, int n) {
  int i = blockIdx.x * blockDim.x + threadIdx.x;
  if (i < n) decay[i] = __expf(-DT / tau[i]);
}

// f32 row-major [R][Kd] -> bf16 FRAG-LINEAR:
// elem (r,k) at ((r>>4)*(Kd/32) + (k>>5))*512 + ((r&15)+(((k>>3)&3)<<4))*8 + (k&7)
// ksh = log2(Kd/32). Writes are out[tid*8] -> perfectly coalesced.
__global__ void cvt_swz(const float* __restrict__ in, bf16_t* __restrict__ out,
                        int R, int Kd, int ksh) {
  const long tid = (long)blockIdx.x * blockDim.x + threadIdx.x;
  const long n = ((long)R * Kd) >> 3;
  if (tid >= n) return;
  const int slice = (int)(tid >> 6);
  const int lane = (int)tid & 63;
  const int g = slice >> ksh;
  const int s = slice & ((1 << ksh) - 1);
  const int r = (g << 4) + (lane & 15);
  const int k = (s << 5) + ((lane >> 4) << 3);
  const float4 v0 = *(const float4*)&in[(long)r * Kd + k];
  const float4 v1 = *(const float4*)&in[(long)r * Kd + k + 4];
  bf16x8 o = {(bf16_t)v0.x, (bf16_t)v0.y, (bf16_t)v0.z, (bf16_t)v0.w,
              (bf16_t)v1.x, (bf16_t)v1.y, (bf16_t)v1.z, (bf16_t)v1.w};
  *(bf16x8*)&out[tid << 3] = o;
}

// C[M,N] = A[M,K] * B[N,K]^T, A and B in FRAG-LINEAR layout (see cvt_swz).
// Round 9: R8's zero-barrier zero-LDS K-loop, but MULTI-BLOCK TLP.
// R8 post-mortem: unique-operand delivery pinned at ~10 B/cyc/CU across ALL
// schedules; all pipes <21% busy; 1 block/CU with 8 lockstep-ish waves =
// too few independent request streams (latency-bound, not rate-bound
// hypothesis). This round: tile 128x128, 256 threads (4 waves, 2Mx2N,
// per-wave 64x64 -- R8's exact per-wave geometry), grid 512 blocks,
// epilogue LDS cut to 32 KB (64x128 f32, two row-passes, R1-verified) ->
// ~3 blocks/CU = 3 independent unsynchronized K-streams per CU (m97, the
// only >20 B/cyc config ever measured, ran 3 blocks/CU).
// hb stays FRAG-LINEAR across steps (R8-verified epilogue addressing).
// EPI=0: ihb(bf16,row-major) = acc + bias1[col] + bias2[col]
// EPI=1: pre = acc + ihb; hn = d*hb_prev + (1-d)*tanh(pre); hb_next=bf16(hn)
//        if writeOut: out_f32 = hn
template <int EPI>
__global__ __launch_bounds__(256, 2) void gemm_nt(
    const bf16_t* __restrict__ A, const bf16_t* __restrict__ Bw, int M, int N,
    int K, const float* __restrict__ bias1, const float* __restrict__ bias2,
    bf16_t* __restrict__ out_ihb, const bf16_t* __restrict__ ihb,
    const float* __restrict__ decay, const bf16_t* __restrict__ hb_prev,
    bf16_t* __restrict__ hb_next, float* __restrict__ out_f32, int writeOut) {
  extern __shared__ char smem[];  // 32768 B, epilogue only (64x128 f32)

  const int tid = threadIdx.x;
  const int lane = tid & 63;
  const int wave = tid >> 6;    // 0..3
  const int waveM = wave >> 1;  // 0..1  (64-row half of 128)
  const int waveN = wave & 1;   // 0..1  (64-col half of 128)

  // XCD swizzle: 512 blocks; XCD grid 2(bx-halves) x 4(by-quarters)
  // -> A read by 2 XCD groups, B by 4 (64 MB compulsory, same as R8)
  const int lin = blockIdx.y * gridDim.x + blockIdx.x;  // 0..511
  const int xcd = lin & 7;
  const int slot_ = lin >> 3;                    // 0..63
  const int bx = (xcd & 1) * 8 + (slot_ & 7);    // 0..15 (N/128)
  const int by = (xcd >> 1) * 8 + (slot_ >> 3);  // 0..31 (M/128)
  const long bRow = (long)by * 128;
  const long bCol = (long)bx * 128;

  // frag-linear bases: row-group slab stride = 16*K elems
  const long KS = (long)K << 4;
  const bf16_t* aP = A + ((long)((bRow >> 4) + waveM * 4)) * KS + (lane << 3);
  const bf16_t* bP = Bw + ((long)((bCol >> 4) + waveN * 4)) * KS + (lane << 3);

  f32x4 acc[4][4] = {};

  auto LD = [&](bf16x8 aF[4], bf16x8 bF[4], int s) {
#pragma unroll
    for (int i = 0; i < 4; ++i)
      aF[i] = *(const bf16x8*)(aP + i * KS + ((long)s << 9));
#pragma unroll
    for (int u = 0; u < 4; ++u)
      bF[u] = *(const bf16x8*)(bP + u * KS + ((long)s << 9));
  };
  auto FM = [&](const bf16x8 aF[4], const bf16x8 bF[4]) {
#pragma unroll
    for (int i = 0; i < 4; ++i)
#pragma unroll
      for (int u = 0; u < 4; ++u)
        acc[i][u] = __builtin_amdgcn_mfma_f32_16x16x32_bf16(aF[i], bF[u],
                                                            acc[i][u], 0, 0, 0);
  };

  // ---- zero-barrier K-loop over NS = K/32 k-slices, 1-slice prefetch ----
  const int NS = K >> 5;  // 32 or 64, even
  bf16x8 a0[4], b0[4], a1[4], b1[4];
  LD(a0, b0, 0);
  int s = 0;
  for (; s + 2 < NS; s += 2) {
    LD(a1, b1, s + 1);
    FM(a0, b0);
    LD(a0, b0, s + 2);
    FM(a1, b1);
  }
  LD(a1, b1, s + 1);  // s == NS-2
  FM(a0, b0);
  FM(a1, b1);

  __syncthreads();  // epilogue LDS phase begins

  // ---- epilogue: 2 passes of 64 rows through swizzled LDS ----
  // C/D layout: col = lane&15, row = (lane>>4)*4 + reg   [measured m89/m91]
  float* Ep = (float*)smem;  // 64 x 128 f32 = 32 KB
  const int eRow = (lane >> 4) << 2;
  const int eCol = lane & 15;

  for (int p = 0; p < 2; ++p) {
    if (p) __syncthreads();  // pass-0 reads done before pass-1 overwrites Ep
    if (waveM == p) {
#pragma unroll
      for (int i = 0; i < 4; ++i)
#pragma unroll
        for (int u = 0; u < 4; ++u)
#pragma unroll
          for (int r = 0; r < 4; ++r) {
            const int rowL = i * 16 + eRow + r;            // 0..63 in band
            const int colL = waveN * 64 + u * 16 + eCol;   // 0..127
            // swizzle: phys = row*128 + ((col + 4*row) & 127)  (2-way max)
            Ep[rowL * 128 + ((colL + 4 * rowL) & 127)] = acc[i][u][r];
          }
    }
    __syncthreads();

    // readers: 2 sub-passes of 32 rows; 16 consecutive cols at (tid&7)*16
#pragma unroll
    for (int r2 = 0; r2 < 2; ++r2) {
      const int rr = r2 * 32 + (tid >> 3);  // local row in band, 0..63
      const int col0 = (tid & 7) * 16;
      float v[16];
#pragma unroll
      for (int c = 0; c < 4; ++c)
        *(f32x4*)&v[c * 4] =
            *(const f32x4*)&Ep[rr * 128 + ((col0 + 4 * c + 4 * rr) & 127)];
      const long grow = bRow + p * 64 + rr;
      const long g = grow * (long)N + bCol + col0;  // row-major addr

      if (EPI == 0) {
        f32x4 b1v[4], b2v[4];
#pragma unroll
        for (int c = 0; c < 4; ++c) {
          b1v[c] = *(const f32x4*)&bias1[bCol + col0 + c * 4];
          b2v[c] = *(const f32x4*)&bias2[bCol + col0 + c * 4];
        }
        bf16x8 o0, o1;
#pragma unroll
        for (int e = 0; e < 8; ++e)
          o0[e] = (bf16_t)(v[e] + b1v[e >> 2][e & 3] + b2v[e >> 2][e & 3]);
#pragma unroll
        for (int e = 0; e < 8; ++e)
          o1[e] = (bf16_t)(v[8 + e] + b1v[2 + (e >> 2)][e & 3] +
                           b2v[2 + (e >> 2)][e & 3]);
        *(bf16x8*)&out_ihb[g] = o0;  // row-major, 16B/lane
        *(bf16x8*)&out_ihb[g + 8] = o1;
      } else {
        // hb is FRAG-LINEAR (Kdim = N). bRow mult of 128, bCol mult of 128
        // -> same lane-bit math as R8 (verified, absmax unchanged).
        const long fg = (grow >> 4) * ((long)N >> 5);
        const int s_ = (int)((bCol + col0) >> 5);
        const int l0 = (int)(grow & 15) + (((col0 >> 3) + 0) & 3) * 16;
        const int l1 = (int)(grow & 15) + (((col0 >> 3) + 1) & 3) * 16;
        const long fo = (fg + s_) << 9;
        const long o0a = fo + (l0 << 3);
        const long o1a = fo + (l1 << 3);
        const bf16x8 ih0 = *(const bf16x8*)&ihb[g];        // row-major
        const bf16x8 ih1 = *(const bf16x8*)&ihb[g + 8];
        const bf16x8 hp0 = *(const bf16x8*)&hb_prev[o0a];  // frag-linear
        const bf16x8 hp1 = *(const bf16x8*)&hb_prev[o1a];
        f32x4 dc[4];
#pragma unroll
        for (int c = 0; c < 4; ++c)
          dc[c] = *(const f32x4*)&decay[bCol + col0 + c * 4];
        float hn[16];
        bf16x8 o0, o1;
#pragma unroll
        for (int e = 0; e < 8; ++e) {
          const float d = dc[e >> 2][e & 3];
          const float th = tanhf(v[e] + (float)ih0[e]);
          hn[e] = d * (float)hp0[e] + (1.0f - d) * th;
          o0[e] = (bf16_t)hn[e];
        }
#pragma unroll
        for (int e = 0; e < 8; ++e) {
          const float d = dc[2 + (e >> 2)][e & 3];
          const float th = tanhf(v[8 + e] + (float)ih1[e]);
          hn[8 + e] = d * (float)hp1[e] + (1.0f - d) * th;
          o1[e] = (bf16_t)hn[8 + e];
        }
        *(bf16x8*)&hb_next[o0a] = o0;  // frag-linear
        *(bf16x8*)&hb_next[o1a] = o1;
        if (writeOut) {
#pragma unroll
          for (int c = 0; c < 4; ++c)
            *(f32x4*)&out_f32[g + c * 4] = *(const f32x4*)&hn[c * 4];
        }
      }
    }
  }
}

extern "C" void kernel_launch(void* const* d_in, const int* in_sizes, int n_in,
                              void* d_out, int out_size, void* d_ws,
                              size_t ws_size, hipStream_t stream) {
  const float* x = (const float*)d_in[0];
  const float* h0 = (const float*)d_in[1];
  const float* W_ih = (const float*)d_in[2];
  const float* b_ih = (const float*)d_in[3];
  const float* W_hh = (const float*)d_in[4];
  const float* b_hh = (const float*)d_in[5];
  const float* tau = (const float*)d_in[6];
  float* hout = (float*)d_out;

  const int B = 4096, I = 1024, H = 2048;

  char* ws = (char*)d_ws;
  bf16_t* ihb = (bf16_t*)ws; ws += (size_t)B * H * 2;   // 16 MB (row-major)
  bf16_t* hb0 = (bf16_t*)ws; ws += (size_t)B * H * 2;   // 16 MB (frag-linear)
  bf16_t* hb1 = (bf16_t*)ws; ws += (size_t)B * H * 2;   // 16 MB (frag-linear)
  bf16_t* xb = (bf16_t*)ws;  ws += (size_t)B * I * 2;   // 8 MB (frag-linear)
  bf16_t* wihb = (bf16_t*)ws; ws += (size_t)H * I * 2;  // 4 MB (frag-linear)
  bf16_t* whhb = (bf16_t*)ws; ws += (size_t)H * H * 2;  // 8 MB (frag-linear)
  float* decay = (float*)ws; ws += (size_t)H * 4;       // 8 KB

  const int LDS_BYTES = 32768;  // epilogue 64x128 f32 -> up to 5 blocks/CU
  (void)hipFuncSetAttribute(reinterpret_cast<const void*>(&gemm_nt<0>),
                            hipFuncAttributeMaxDynamicSharedMemorySize,
                            LDS_BYTES);
  (void)hipFuncSetAttribute(reinterpret_cast<const void*>(&gemm_nt<1>),
                            hipFuncAttributeMaxDynamicSharedMemorySize,
                            LDS_BYTES);

  // one-shot conversions into frag-linear layout (ksh = log2(Kd/32))
  {
    long n;
    n = (long)B * I / 8;
    cvt_swz<<<(int)((n + 255) / 256), 256, 0, stream>>>(x, xb, B, I, 5);
    n = (long)H * I / 8;
    cvt_swz<<<(int)((n + 255) / 256), 256, 0, stream>>>(W_ih, wihb, H, I, 5);
    n = (long)H * H / 8;
    cvt_swz<<<(int)((n + 255) / 256), 256, 0, stream>>>(W_hh, whhb, H, H, 6);
    n = (long)B * H / 8;
    cvt_swz<<<(int)((n + 255) / 256), 256, 0, stream>>>(h0, hb0, B, H, 6);
  }
  make_decay<<<(H + 255) / 256, 256, 0, stream>>>(tau, decay, H);

  dim3 grid(H / 128, B / 128);  // (16, 32) = 512 blocks = 2+/CU
  // ihb = x @ W_ih^T + b_ih + b_hh   (fold both biases once, store bf16)
  gemm_nt<0><<<grid, 256, LDS_BYTES, stream>>>(
      xb, wihb, B, H, I, b_ih, b_hh, ihb, nullptr, nullptr, nullptr, nullptr,
      nullptr, 0);

  bf16_t* hb[2] = {hb0, hb1};
  for (int s = 0; s < NUM_STEPS; ++s) {
    gemm_nt<1><<<grid, 256, LDS_BYTES, stream>>>(
        hb[s & 1], whhb, B, H, H, nullptr, nullptr, nullptr, ihb, decay,
        hb[s & 1], hb[(s + 1) & 1], hout, (s == NUM_STEPS - 1) ? 1 : 0);
  }
}